// Round 15
// baseline (416.390 us; speedup 1.0000x reference)
//
#include <hip/hip_runtime.h>
#include <hip/hip_bf16.h>

using bf16 = __hip_bfloat16;
typedef __attribute__((ext_vector_type(8))) short bf16x8;
typedef __attribute__((ext_vector_type(4))) float f32x4;

__device__ __forceinline__ float lo2f(unsigned u) { return __uint_as_float(u << 16); }
__device__ __forceinline__ float hi2f(unsigned u) { return __uint_as_float(u & 0xffff0000u); }
__device__ __forceinline__ unsigned pack_bf2(float a, float b) {
    bf16 t0 = __float2bfloat16(a), t1 = __float2bfloat16(b);
    return (unsigned)*(unsigned short*)&t0 | ((unsigned)*(unsigned short*)&t1 << 16);
}

// -------- prep: hist over dst + graph boundaries (fused) --------
__global__ void prep(const int* __restrict__ ei, int E, const int* __restrict__ batch,
                     int N, int G, int* __restrict__ deg, int* __restrict__ gstart)
{
    int i = blockIdx.x * blockDim.x + threadIdx.x;
    if (i < E) atomicAdd(&deg[ei[E + i]], 1);
    if (i < N) {
        int b = batch[i];
        int bp = (i == 0) ? -1 : batch[i - 1];
        for (int q = bp + 1; q <= b; ++q) gstart[q] = i;
        if (i == N - 1)
            for (int q = b + 1; q <= G; ++q) gstart[q] = N;
    }
}

// -------- scan (3 kernels), dinv fused into scan1 --------
__global__ __launch_bounds__(256)
void scan1d(const int* __restrict__ deg, int N, int* __restrict__ rowptr,
            int* __restrict__ bsum, float* __restrict__ dinv) {
    __shared__ int sm[256];
    int t = threadIdx.x;
    int i = blockIdx.x * 256 + t;
    int v = (i < N) ? deg[i] : 0;
    if (i < N) dinv[i] = rsqrtf((float)(v + 1));   // +1 self-loop
    sm[t] = v;
    __syncthreads();
#pragma unroll
    for (int off = 1; off < 256; off <<= 1) {
        int x = (t >= off) ? sm[t - off] : 0;
        __syncthreads();
        sm[t] += x;
        __syncthreads();
    }
    if (i < N) rowptr[i] = sm[t] - v;
    if (t == 255) bsum[blockIdx.x] = sm[255];
}

__global__ __launch_bounds__(256)
void scan2(int* __restrict__ bsum, int B, int N, int* __restrict__ rowptr) {
    __shared__ int sm[256];
    int t = threadIdx.x;
    int v = (t < B) ? bsum[t] : 0;
    sm[t] = v;
    __syncthreads();
#pragma unroll
    for (int off = 1; off < 256; off <<= 1) {
        int x = (t >= off) ? sm[t - off] : 0;
        __syncthreads();
        sm[t] += x;
        __syncthreads();
    }
    if (t < B) bsum[t] = sm[t] - v;
    if (t == 255) rowptr[N] = sm[255];
}

__global__ __launch_bounds__(256)
void scan3(int N, const int* __restrict__ bsum, int* __restrict__ rowptr) {
    int i = blockIdx.x * 256 + threadIdx.x;
    if (i < N) rowptr[i] += bsum[blockIdx.x];
}

// -------- CSR fill (naive: 50000 private write fronts; R11's shared-front
// bucketing regressed 3.5x on 8 non-coherent XCDs) --------
__global__ void fill_col(const int* __restrict__ ei, int E, const int* __restrict__ rowptr,
                         int* __restrict__ cursor, int* __restrict__ col) {
    int e = blockIdx.x * blockDim.x + threadIdx.x;
    if (e >= E) return;
    int s = ei[e];
    int d = ei[E + e];
    int p = atomicAdd(&cursor[d], 1);
    col[rowptr[d] + p] = s;
}

#define LDK 136

// -------- layer-1 GEMM: reads fp32 x directly, bf16 MFMA, fp32 accum --------
__global__ __launch_bounds__(256)
void gemm1_f32(const float* __restrict__ x, const float* __restrict__ W,
               const float* __restrict__ dinv, int N, bf16* __restrict__ g)
{
    __shared__ short Wt[128 * LDK];
    for (int i = threadIdx.x; i < 128 * 128; i += 256) {
        int k = i >> 7, n = i & 127;
        bf16 b = __float2bfloat16(W[i]);   // exact: values bf16-quantized
        Wt[n * LDK + k] = *(short*)&b;
    }
    __syncthreads();

    int wave = threadIdx.x >> 6;
    int lane = threadIdx.x & 63;
    int ln   = lane & 15;
    int quad = lane >> 4;
    int m0 = (blockIdx.x * 4 + wave) * 16;
    if (m0 >= N) return;

    int row = m0 + ln;
    if (row >= N) row = N - 1;
    const float* hrow = x + (size_t)row * 128;

    bf16x8 a[4];
#pragma unroll
    for (int kk = 0; kk < 4; ++kk) {
        float4 f0 = *(const float4*)(hrow + kk * 32 + quad * 8);
        float4 f1 = *(const float4*)(hrow + kk * 32 + quad * 8 + 4);
        float fv[8] = {f0.x, f0.y, f0.z, f0.w, f1.x, f1.y, f1.z, f1.w};
#pragma unroll
        for (int j = 0; j < 8; ++j) {
            bf16 tb = __float2bfloat16(fv[j]);
            ((short*)&a[kk])[j] = *(short*)&tb;
        }
    }

    f32x4 c[8];
#pragma unroll
    for (int nt = 0; nt < 8; ++nt) c[nt] = (f32x4){0.f, 0.f, 0.f, 0.f};
#pragma unroll
    for (int kk = 0; kk < 4; ++kk)
#pragma unroll
        for (int nt = 0; nt < 8; ++nt) {
            bf16x8 b = *(const bf16x8*)&Wt[(nt * 16 + ln) * LDK + kk * 32 + quad * 8];
            c[nt] = __builtin_amdgcn_mfma_f32_16x16x32_bf16(a[kk], b, c[nt], 0, 0, 0);
        }
#pragma unroll
    for (int r = 0; r < 4; ++r) {
        int m = m0 + quad * 4 + r;
        if (m < N) {
            float dv = dinv[m];
#pragma unroll
            for (int nt = 0; nt < 8; ++nt) {
                bf16 val = __float2bfloat16(c[nt][r] * dv);
                ((unsigned short*)g)[(size_t)m * 128 + nt * 16 + ln] = *(unsigned short*)&val;
            }
        }
    }
}

// -------- MFMA GEMM (bf16 h in): g = dinv * (h @ W) --------
__global__ __launch_bounds__(256)
void gemm_mfma(const bf16* __restrict__ hin, const float* __restrict__ W,
               const float* __restrict__ dinv, int N, bf16* __restrict__ g)
{
    __shared__ short Wt[128 * LDK];
    for (int i = threadIdx.x; i < 128 * 128; i += 256) {
        int k = i >> 7, n = i & 127;
        bf16 b = __float2bfloat16(W[i]);
        Wt[n * LDK + k] = *(short*)&b;
    }
    __syncthreads();

    int wave = threadIdx.x >> 6;
    int lane = threadIdx.x & 63;
    int ln   = lane & 15;
    int quad = lane >> 4;
    int m0 = (blockIdx.x * 4 + wave) * 16;
    if (m0 >= N) return;

    int row = m0 + ln;
    if (row >= N) row = N - 1;
    const short* hrow = (const short*)hin + (size_t)row * 128;

    bf16x8 a[4];
#pragma unroll
    for (int kk = 0; kk < 4; ++kk)
        a[kk] = *(const bf16x8*)(hrow + kk * 32 + quad * 8);

    f32x4 c[8];
#pragma unroll
    for (int nt = 0; nt < 8; ++nt) c[nt] = (f32x4){0.f, 0.f, 0.f, 0.f};
#pragma unroll
    for (int kk = 0; kk < 4; ++kk)
#pragma unroll
        for (int nt = 0; nt < 8; ++nt) {
            bf16x8 b = *(const bf16x8*)&Wt[(nt * 16 + ln) * LDK + kk * 32 + quad * 8];
            c[nt] = __builtin_amdgcn_mfma_f32_16x16x32_bf16(a[kk], b, c[nt], 0, 0, 0);
        }
#pragma unroll
    for (int r = 0; r < 4; ++r) {
        int m = m0 + quad * 4 + r;
        if (m < N) {
            float dv = dinv[m];
#pragma unroll
            for (int nt = 0; nt < 8; ++nt) {
                bf16 val = __float2bfloat16(c[nt][r] * dv);
                ((unsigned short*)g)[(size_t)m * 128 + nt * 16 + ln] = *(unsigned short*)&val;
            }
        }
    }
}

// -------- gather: h[v] = [relu](dinv[v]*(g[v] + sum_in g[s]) + bias) --------
__global__ __launch_bounds__(256)
void gather16(const bf16* __restrict__ g, const int* __restrict__ rowptr,
              const int* __restrict__ col, const float* __restrict__ dinv,
              const float* __restrict__ bias, int N, int do_relu, bf16* __restrict__ hout)
{
    int v = blockIdx.x * 4 + (threadIdx.x >> 6);
    if (v >= N) return;
    int lane = threadIdx.x & 63;
    const unsigned* gp = (const unsigned*)g;

    unsigned su = gp[(size_t)v * 64 + lane];
    float s0 = lo2f(su), s1 = hi2f(su);

    int beg = rowptr[v], end = rowptr[v + 1];
    int i = beg;
    for (; i + 8 <= end; i += 8) {
        int cc[8];
#pragma unroll
        for (int j = 0; j < 8; ++j) cc[j] = col[i + j];
        unsigned uu[8];
#pragma unroll
        for (int j = 0; j < 8; ++j) uu[j] = gp[(size_t)cc[j] * 64 + lane];
#pragma unroll
        for (int j = 0; j < 8; ++j) { s0 += lo2f(uu[j]); s1 += hi2f(uu[j]); }
    }
    for (; i + 4 <= end; i += 4) {
        int c0 = col[i], c1 = col[i + 1], c2 = col[i + 2], c3 = col[i + 3];
        unsigned u0 = gp[(size_t)c0 * 64 + lane];
        unsigned u1 = gp[(size_t)c1 * 64 + lane];
        unsigned u2 = gp[(size_t)c2 * 64 + lane];
        unsigned u3 = gp[(size_t)c3 * 64 + lane];
        s0 += lo2f(u0) + lo2f(u1) + lo2f(u2) + lo2f(u3);
        s1 += hi2f(u0) + hi2f(u1) + hi2f(u2) + hi2f(u3);
    }
    for (; i < end; ++i) {
        unsigned u = gp[(size_t)col[i] * 64 + lane];
        s0 += lo2f(u);
        s1 += hi2f(u);
    }
    float dv = dinv[v];
    float2 bb = ((const float2*)bias)[lane];
    float r0 = fmaf(dv, s0, bb.x);
    float r1 = fmaf(dv, s1, bb.y);
    if (do_relu) { r0 = fmaxf(r0, 0.f); r1 = fmaxf(r1, 0.f); }
    ((unsigned*)hout)[(size_t)v * 64 + lane] = pack_bf2(r0, r1);
}

// -------- parallel mean pool (partial sums + run-flush atomics) --------
#define PCH 32
__global__ __launch_bounds__(128)
void pool_part(const bf16* __restrict__ h, const int* __restrict__ batch, int N,
               float* __restrict__ pooled)
{
    int c0 = blockIdx.x * PCH;
    if (c0 >= N) return;
    int f = threadIdx.x;
    int end = min(c0 + PCH, N);
    int cur = batch[c0];
    float acc = 0.f;
    for (int v = c0; v < end; ++v) {
        int b = batch[v];
        if (b != cur) {
            atomicAdd(&pooled[cur * 128 + f], acc);
            acc = 0.f;
            cur = b;
        }
        acc += __bfloat162float(h[(size_t)v * 128 + f]);
    }
    atomicAdd(&pooled[cur * 128 + f], acc);
}

// -------- MLP head, stage 1: O = relu(P @ Wm1 + bm1), 4 graphs/block --------
// Each Wm1 load feeds 4 FMAs; mean-div folded into the P staging.
__global__ __launch_bounds__(256)
void head1(const float* __restrict__ pooled, const int* __restrict__ gstart,
           const float* __restrict__ Wm1, const float* __restrict__ bm1,
           float* __restrict__ O)
{
    __shared__ float Ps[4][128];
    int g0 = blockIdx.x * 4;
    int t = threadIdx.x;
    for (int i = t; i < 4 * 128; i += 256) {
        int g = i >> 7, f = i & 127;
        int gg = g0 + g;
        int c = gstart[gg + 1] - gstart[gg];
        Ps[g][f] = pooled[gg * 128 + f] / (float)(c > 0 ? c : 1);
    }
    __syncthreads();
    float acc[4] = {0.f, 0.f, 0.f, 0.f};
#pragma unroll 8
    for (int k = 0; k < 128; ++k) {
        float w = Wm1[k * 256 + t];
#pragma unroll
        for (int g = 0; g < 4; ++g) acc[g] = fmaf(Ps[g][k], w, acc[g]);
    }
    float b = bm1[t];
#pragma unroll
    for (int g = 0; g < 4; ++g)
        O[(size_t)(g0 + g) * 256 + t] = fmaxf(acc[g] + b, 0.f);
}

// -------- MLP head, stage 2: out = O @ Wm2 + bm2, 8 graphs x 256-j tile/block --------
// Each Wm2 load feeds 8 FMAs; k-chain 256 loads unrolled x8.
__global__ __launch_bounds__(256)
void head2(const float* __restrict__ O, const float* __restrict__ Wm2,
           const float* __restrict__ bm2, float* __restrict__ out)
{
    __shared__ float Os[8][256];
    int jt = blockIdx.x;          // 0..2
    int g0 = blockIdx.y * 8;      // 0..248
    int t = threadIdx.x;
    int j = jt * 256 + t;
    for (int i = t; i < 8 * 256; i += 256) {
        int g = i >> 8, k = i & 255;
        Os[g][k] = O[(size_t)(g0 + g) * 256 + k];
    }
    __syncthreads();
    float acc[8] = {0.f, 0.f, 0.f, 0.f, 0.f, 0.f, 0.f, 0.f};
#pragma unroll 8
    for (int k = 0; k < 256; ++k) {
        float w = Wm2[k * 768 + j];
#pragma unroll
        for (int g = 0; g < 8; ++g) acc[g] = fmaf(Os[g][k], w, acc[g]);
    }
    float b = bm2[j];
#pragma unroll
    for (int g = 0; g < 8; ++g)
        out[(size_t)(g0 + g) * 768 + j] = acc[g] + b;
}

extern "C" void kernel_launch(void* const* d_in, const int* in_sizes, int n_in,
                              void* d_out, int out_size, void* d_ws, size_t ws_size,
                              hipStream_t stream)
{
    const float* x     = (const float*)d_in[0];
    const int*   ei    = (const int*)d_in[1];   // [2,E] int32: src row then dst row
    const int*   batch = (const int*)d_in[2];
    const float *W1 = (const float*)d_in[3],  *bb1 = (const float*)d_in[4];
    const float *W2 = (const float*)d_in[5],  *bb2 = (const float*)d_in[6];
    const float *W3 = (const float*)d_in[7],  *bb3 = (const float*)d_in[8];
    const float *Wm1 = (const float*)d_in[9],  *bm1 = (const float*)d_in[10];
    const float *Wm2 = (const float*)d_in[11], *bm2 = (const float*)d_in[12];

    const int N = in_sizes[2];        // 50000
    const int E = in_sizes[1] / 2;    // 800000
    const int G = out_size / 768;     // 256

    char* wp = (char*)d_ws;
    bf16* bufG   = (bf16*)wp;  wp += (size_t)N * 128 * 2;   // 12.8 MB (g)
    bf16* bufH   = (bf16*)wp;  wp += (size_t)N * 128 * 2;   // 12.8 MB (h)
    int*  col    = (int*)wp;   wp += (size_t)E * 4;         // 3.2 MB
    int*  rowptr = (int*)wp;   wp += (size_t)(N + 1) * 4;
    // contiguous zero region: deg | cursor | pooled (single memset)
    int*  deg    = (int*)wp;   wp += (size_t)N * 4;
    int*  cursor = (int*)wp;   wp += (size_t)N * 4;
    float* pooled= (float*)wp; wp += (size_t)G * 128 * 4;
    float* dinv  = (float*)wp; wp += (size_t)N * 4;
    int*  gstart = (int*)wp;   wp += (size_t)(G + 1) * 4;
    float* Obuf  = (float*)wp; wp += (size_t)G * 256 * 4;
    int*  bsum   = (int*)wp;   wp += 256 * 4;

    hipMemsetAsync(deg, 0, (size_t)N * 4 + (size_t)N * 4 + (size_t)G * 128 * 4, stream);

    const int SB = (N + 255) / 256;

    prep<<<(E + 255) / 256, 256, 0, stream>>>(ei, E, batch, N, G, deg, gstart);
    scan1d<<<SB, 256, 0, stream>>>(deg, N, rowptr, bsum, dinv);
    scan2<<<1, 256, 0, stream>>>(bsum, SB, N, rowptr);
    scan3<<<SB, 256, 0, stream>>>(N, bsum, rowptr);
    fill_col<<<(E + 255) / 256, 256, 0, stream>>>(ei, E, rowptr, cursor, col);

    const int gemm_grid   = (N + 63) / 64;
    const int gather_grid = (N + 3) / 4;

    // layer 1: x (fp32) -> bufG -> bufH
    gemm1_f32<<<gemm_grid, 256, 0, stream>>>(x, W1, dinv, N, bufG);
    gather16<<<gather_grid, 256, 0, stream>>>(bufG, rowptr, col, dinv, bb1, N, 1, bufH);
    // layer 2
    gemm_mfma<<<gemm_grid, 256, 0, stream>>>(bufH, W2, dinv, N, bufG);
    gather16<<<gather_grid, 256, 0, stream>>>(bufG, rowptr, col, dinv, bb2, N, 1, bufH);
    // layer 3 (no relu)
    gemm_mfma<<<gemm_grid, 256, 0, stream>>>(bufH, W3, dinv, N, bufG);
    gather16<<<gather_grid, 256, 0, stream>>>(bufG, rowptr, col, dinv, bb3, N, 0, bufH);

    // pooling + MLP head (restructured for load reuse / TLP)
    pool_part<<<(N + PCH - 1) / PCH, 128, 0, stream>>>(bufH, batch, N, pooled);
    head1<<<G / 4, 256, 0, stream>>>(pooled, gstart, Wm1, bm1, Obuf);
    head2<<<dim3(3, G / 8), 256, 0, stream>>>(Obuf, Wm2, bm2, (float*)d_out);
}

// Round 16
// 368.980 us; speedup vs baseline: 1.1285x; 1.1285x over previous
//
#include <hip/hip_runtime.h>
#include <hip/hip_bf16.h>

using bf16 = __hip_bfloat16;
typedef __attribute__((ext_vector_type(8))) short bf16x8;
typedef __attribute__((ext_vector_type(4))) float f32x4;

__device__ __forceinline__ float lo2f(unsigned u) { return __uint_as_float(u << 16); }
__device__ __forceinline__ float hi2f(unsigned u) { return __uint_as_float(u & 0xffff0000u); }
__device__ __forceinline__ unsigned pack_bf2(float a, float b) {
    bf16 t0 = __float2bfloat16(a), t1 = __float2bfloat16(b);
    return (unsigned)*(unsigned short*)&t0 | ((unsigned)*(unsigned short*)&t1 << 16);
}

// -------- prep: hist over dst + graph boundaries (fused) --------
__global__ void prep(const int* __restrict__ ei, int E, const int* __restrict__ batch,
                     int N, int G, int* __restrict__ deg, int* __restrict__ gstart)
{
    int i = blockIdx.x * blockDim.x + threadIdx.x;
    if (i < E) atomicAdd(&deg[ei[E + i]], 1);
    if (i < N) {
        int b = batch[i];
        int bp = (i == 0) ? -1 : batch[i - 1];
        for (int q = bp + 1; q <= b; ++q) gstart[q] = i;
        if (i == N - 1)
            for (int q = b + 1; q <= G; ++q) gstart[q] = N;
    }
}

// -------- scan (3 kernels), dinv fused into scan1 --------
__global__ __launch_bounds__(256)
void scan1d(const int* __restrict__ deg, int N, int* __restrict__ rowptr,
            int* __restrict__ bsum, float* __restrict__ dinv) {
    __shared__ int sm[256];
    int t = threadIdx.x;
    int i = blockIdx.x * 256 + t;
    int v = (i < N) ? deg[i] : 0;
    if (i < N) dinv[i] = rsqrtf((float)(v + 1));   // +1 self-loop
    sm[t] = v;
    __syncthreads();
#pragma unroll
    for (int off = 1; off < 256; off <<= 1) {
        int x = (t >= off) ? sm[t - off] : 0;
        __syncthreads();
        sm[t] += x;
        __syncthreads();
    }
    if (i < N) rowptr[i] = sm[t] - v;
    if (t == 255) bsum[blockIdx.x] = sm[255];
}

__global__ __launch_bounds__(256)
void scan2(int* __restrict__ bsum, int B, int N, int* __restrict__ rowptr) {
    __shared__ int sm[256];
    int t = threadIdx.x;
    int v = (t < B) ? bsum[t] : 0;
    sm[t] = v;
    __syncthreads();
#pragma unroll
    for (int off = 1; off < 256; off <<= 1) {
        int x = (t >= off) ? sm[t - off] : 0;
        __syncthreads();
        sm[t] += x;
        __syncthreads();
    }
    if (t < B) bsum[t] = sm[t] - v;
    if (t == 255) rowptr[N] = sm[255];
}

__global__ __launch_bounds__(256)
void scan3(int N, const int* __restrict__ bsum, int* __restrict__ rowptr) {
    int i = blockIdx.x * 256 + threadIdx.x;
    if (i < N) rowptr[i] += bsum[blockIdx.x];
}

// -------- CSR fill (naive: 50000 private write fronts; R11's shared-front
// bucketing regressed 3.5x on 8 non-coherent XCDs) --------
__global__ void fill_col(const int* __restrict__ ei, int E, const int* __restrict__ rowptr,
                         int* __restrict__ cursor, int* __restrict__ col) {
    int e = blockIdx.x * blockDim.x + threadIdx.x;
    if (e >= E) return;
    int s = ei[e];
    int d = ei[E + e];
    int p = atomicAdd(&cursor[d], 1);
    col[rowptr[d] + p] = s;
}

#define LDK 136

// -------- layer-1 GEMM: reads fp32 x directly, bf16 MFMA, fp32 accum --------
__global__ __launch_bounds__(256)
void gemm1_f32(const float* __restrict__ x, const float* __restrict__ W,
               const float* __restrict__ dinv, int N, bf16* __restrict__ g)
{
    __shared__ short Wt[128 * LDK];
    for (int i = threadIdx.x; i < 128 * 128; i += 256) {
        int k = i >> 7, n = i & 127;
        bf16 b = __float2bfloat16(W[i]);   // exact: values bf16-quantized
        Wt[n * LDK + k] = *(short*)&b;
    }
    __syncthreads();

    int wave = threadIdx.x >> 6;
    int lane = threadIdx.x & 63;
    int ln   = lane & 15;
    int quad = lane >> 4;
    int m0 = (blockIdx.x * 4 + wave) * 16;
    if (m0 >= N) return;

    int row = m0 + ln;
    if (row >= N) row = N - 1;
    const float* hrow = x + (size_t)row * 128;

    bf16x8 a[4];
#pragma unroll
    for (int kk = 0; kk < 4; ++kk) {
        float4 f0 = *(const float4*)(hrow + kk * 32 + quad * 8);
        float4 f1 = *(const float4*)(hrow + kk * 32 + quad * 8 + 4);
        float fv[8] = {f0.x, f0.y, f0.z, f0.w, f1.x, f1.y, f1.z, f1.w};
#pragma unroll
        for (int j = 0; j < 8; ++j) {
            bf16 tb = __float2bfloat16(fv[j]);
            ((short*)&a[kk])[j] = *(short*)&tb;
        }
    }

    f32x4 c[8];
#pragma unroll
    for (int nt = 0; nt < 8; ++nt) c[nt] = (f32x4){0.f, 0.f, 0.f, 0.f};
#pragma unroll
    for (int kk = 0; kk < 4; ++kk)
#pragma unroll
        for (int nt = 0; nt < 8; ++nt) {
            bf16x8 b = *(const bf16x8*)&Wt[(nt * 16 + ln) * LDK + kk * 32 + quad * 8];
            c[nt] = __builtin_amdgcn_mfma_f32_16x16x32_bf16(a[kk], b, c[nt], 0, 0, 0);
        }
#pragma unroll
    for (int r = 0; r < 4; ++r) {
        int m = m0 + quad * 4 + r;
        if (m < N) {
            float dv = dinv[m];
#pragma unroll
            for (int nt = 0; nt < 8; ++nt) {
                bf16 val = __float2bfloat16(c[nt][r] * dv);
                ((unsigned short*)g)[(size_t)m * 128 + nt * 16 + ln] = *(unsigned short*)&val;
            }
        }
    }
}

// -------- MFMA GEMM (bf16 h in): g = dinv * (h @ W) --------
__global__ __launch_bounds__(256)
void gemm_mfma(const bf16* __restrict__ hin, const float* __restrict__ W,
               const float* __restrict__ dinv, int N, bf16* __restrict__ g)
{
    __shared__ short Wt[128 * LDK];
    for (int i = threadIdx.x; i < 128 * 128; i += 256) {
        int k = i >> 7, n = i & 127;
        bf16 b = __float2bfloat16(W[i]);
        Wt[n * LDK + k] = *(short*)&b;
    }
    __syncthreads();

    int wave = threadIdx.x >> 6;
    int lane = threadIdx.x & 63;
    int ln   = lane & 15;
    int quad = lane >> 4;
    int m0 = (blockIdx.x * 4 + wave) * 16;
    if (m0 >= N) return;

    int row = m0 + ln;
    if (row >= N) row = N - 1;
    const short* hrow = (const short*)hin + (size_t)row * 128;

    bf16x8 a[4];
#pragma unroll
    for (int kk = 0; kk < 4; ++kk)
        a[kk] = *(const bf16x8*)(hrow + kk * 32 + quad * 8);

    f32x4 c[8];
#pragma unroll
    for (int nt = 0; nt < 8; ++nt) c[nt] = (f32x4){0.f, 0.f, 0.f, 0.f};
#pragma unroll
    for (int kk = 0; kk < 4; ++kk)
#pragma unroll
        for (int nt = 0; nt < 8; ++nt) {
            bf16x8 b = *(const bf16x8*)&Wt[(nt * 16 + ln) * LDK + kk * 32 + quad * 8];
            c[nt] = __builtin_amdgcn_mfma_f32_16x16x32_bf16(a[kk], b, c[nt], 0, 0, 0);
        }
#pragma unroll
    for (int r = 0; r < 4; ++r) {
        int m = m0 + quad * 4 + r;
        if (m < N) {
            float dv = dinv[m];
#pragma unroll
            for (int nt = 0; nt < 8; ++nt) {
                bf16 val = __float2bfloat16(c[nt][r] * dv);
                ((unsigned short*)g)[(size_t)m * 128 + nt * 16 + ln] = *(unsigned short*)&val;
            }
        }
    }
}

// -------- gather: h[v] = [relu](dinv[v]*(g[v] + sum_in g[s]) + bias) --------
__global__ __launch_bounds__(256)
void gather16(const bf16* __restrict__ g, const int* __restrict__ rowptr,
              const int* __restrict__ col, const float* __restrict__ dinv,
              const float* __restrict__ bias, int N, int do_relu, bf16* __restrict__ hout)
{
    int v = blockIdx.x * 4 + (threadIdx.x >> 6);
    if (v >= N) return;
    int lane = threadIdx.x & 63;
    const unsigned* gp = (const unsigned*)g;

    unsigned su = gp[(size_t)v * 64 + lane];
    float s0 = lo2f(su), s1 = hi2f(su);

    int beg = rowptr[v], end = rowptr[v + 1];
    int i = beg;
    for (; i + 8 <= end; i += 8) {
        int cc[8];
#pragma unroll
        for (int j = 0; j < 8; ++j) cc[j] = col[i + j];
        unsigned uu[8];
#pragma unroll
        for (int j = 0; j < 8; ++j) uu[j] = gp[(size_t)cc[j] * 64 + lane];
#pragma unroll
        for (int j = 0; j < 8; ++j) { s0 += lo2f(uu[j]); s1 += hi2f(uu[j]); }
    }
    for (; i + 4 <= end; i += 4) {
        int c0 = col[i], c1 = col[i + 1], c2 = col[i + 2], c3 = col[i + 3];
        unsigned u0 = gp[(size_t)c0 * 64 + lane];
        unsigned u1 = gp[(size_t)c1 * 64 + lane];
        unsigned u2 = gp[(size_t)c2 * 64 + lane];
        unsigned u3 = gp[(size_t)c3 * 64 + lane];
        s0 += lo2f(u0) + lo2f(u1) + lo2f(u2) + lo2f(u3);
        s1 += hi2f(u0) + hi2f(u1) + hi2f(u2) + hi2f(u3);
    }
    for (; i < end; ++i) {
        unsigned u = gp[(size_t)col[i] * 64 + lane];
        s0 += lo2f(u);
        s1 += hi2f(u);
    }
    float dv = dinv[v];
    float2 bb = ((const float2*)bias)[lane];
    float r0 = fmaf(dv, s0, bb.x);
    float r1 = fmaf(dv, s1, bb.y);
    if (do_relu) { r0 = fmaxf(r0, 0.f); r1 = fmaxf(r1, 0.f); }
    ((unsigned*)hout)[(size_t)v * 64 + lane] = pack_bf2(r0, r1);
}

// -------- parallel mean pool (partial sums + run-flush atomics) --------
#define PCH 32
__global__ __launch_bounds__(128)
void pool_part(const bf16* __restrict__ h, const int* __restrict__ batch, int N,
               float* __restrict__ pooled)
{
    int c0 = blockIdx.x * PCH;
    if (c0 >= N) return;
    int f = threadIdx.x;
    int end = min(c0 + PCH, N);
    int cur = batch[c0];
    float acc = 0.f;
    for (int v = c0; v < end; ++v) {
        int b = batch[v];
        if (b != cur) {
            atomicAdd(&pooled[cur * 128 + f], acc);
            acc = 0.f;
            cur = b;
        }
        acc += __bfloat162float(h[(size_t)v * 128 + f]);
    }
    atomicAdd(&pooled[cur * 128 + f], acc);
}

// -------- MLP head, R12-style high-TLP (1 block/graph; 12 waves/CU in stage 2).
// R14 (1 block total per graph-head) and R15 (96 blocks) both latency-bound at
// ~100 µs — TLP beats load-reuse for these tiny GEMMs. --------
__global__ __launch_bounds__(256)
void mlp1g(const float* __restrict__ pooled, const int* __restrict__ gstart,
           const float* __restrict__ Wm1, const float* __restrict__ bm1,
           float* __restrict__ O)
{
    __shared__ float Ps[128];
    int gg = blockIdx.x, j = threadIdx.x;
    if (j < 128) {
        int c = gstart[gg + 1] - gstart[gg];
        Ps[j] = pooled[gg * 128 + j] / (float)(c > 0 ? c : 1);
    }
    __syncthreads();
    float s = 0.f;
#pragma unroll 4
    for (int k = 0; k < 128; ++k) s = fmaf(Ps[k], Wm1[k * 256 + j], s);
    O[(size_t)gg * 256 + j] = fmaxf(s + bm1[j], 0.f);
}

__global__ __launch_bounds__(768)
void mlp2g(const float* __restrict__ O, const float* __restrict__ Wm2,
           const float* __restrict__ bm2, float* __restrict__ out)
{
    __shared__ float Os[256];
    int gg = blockIdx.x, j = threadIdx.x;
    if (j < 256) Os[j] = O[(size_t)gg * 256 + j];
    __syncthreads();
    float s = 0.f;
#pragma unroll 4
    for (int k = 0; k < 256; ++k) s = fmaf(Os[k], Wm2[k * 768 + j], s);
    out[(size_t)gg * 768 + j] = s + bm2[j];
}

extern "C" void kernel_launch(void* const* d_in, const int* in_sizes, int n_in,
                              void* d_out, int out_size, void* d_ws, size_t ws_size,
                              hipStream_t stream)
{
    const float* x     = (const float*)d_in[0];
    const int*   ei    = (const int*)d_in[1];   // [2,E] int32: src row then dst row
    const int*   batch = (const int*)d_in[2];
    const float *W1 = (const float*)d_in[3],  *bb1 = (const float*)d_in[4];
    const float *W2 = (const float*)d_in[5],  *bb2 = (const float*)d_in[6];
    const float *W3 = (const float*)d_in[7],  *bb3 = (const float*)d_in[8];
    const float *Wm1 = (const float*)d_in[9],  *bm1 = (const float*)d_in[10];
    const float *Wm2 = (const float*)d_in[11], *bm2 = (const float*)d_in[12];

    const int N = in_sizes[2];        // 50000
    const int E = in_sizes[1] / 2;    // 800000
    const int G = out_size / 768;     // 256

    char* wp = (char*)d_ws;
    bf16* bufG   = (bf16*)wp;  wp += (size_t)N * 128 * 2;   // 12.8 MB (g)
    bf16* bufH   = (bf16*)wp;  wp += (size_t)N * 128 * 2;   // 12.8 MB (h)
    int*  col    = (int*)wp;   wp += (size_t)E * 4;         // 3.2 MB
    int*  rowptr = (int*)wp;   wp += (size_t)(N + 1) * 4;
    // contiguous zero region: deg | cursor | pooled (single memset)
    int*  deg    = (int*)wp;   wp += (size_t)N * 4;
    int*  cursor = (int*)wp;   wp += (size_t)N * 4;
    float* pooled= (float*)wp; wp += (size_t)G * 128 * 4;
    float* dinv  = (float*)wp; wp += (size_t)N * 4;
    int*  gstart = (int*)wp;   wp += (size_t)(G + 1) * 4;
    float* Obuf  = (float*)wp; wp += (size_t)G * 256 * 4;
    int*  bsum   = (int*)wp;   wp += 256 * 4;

    hipMemsetAsync(deg, 0, (size_t)N * 4 + (size_t)N * 4 + (size_t)G * 128 * 4, stream);

    const int SB = (N + 255) / 256;

    prep<<<(E + 255) / 256, 256, 0, stream>>>(ei, E, batch, N, G, deg, gstart);
    scan1d<<<SB, 256, 0, stream>>>(deg, N, rowptr, bsum, dinv);
    scan2<<<1, 256, 0, stream>>>(bsum, SB, N, rowptr);
    scan3<<<SB, 256, 0, stream>>>(N, bsum, rowptr);
    fill_col<<<(E + 255) / 256, 256, 0, stream>>>(ei, E, rowptr, cursor, col);

    const int gemm_grid   = (N + 63) / 64;
    const int gather_grid = (N + 3) / 4;

    // layer 1: x (fp32) -> bufG -> bufH
    gemm1_f32<<<gemm_grid, 256, 0, stream>>>(x, W1, dinv, N, bufG);
    gather16<<<gather_grid, 256, 0, stream>>>(bufG, rowptr, col, dinv, bb1, N, 1, bufH);
    // layer 2
    gemm_mfma<<<gemm_grid, 256, 0, stream>>>(bufH, W2, dinv, N, bufG);
    gather16<<<gather_grid, 256, 0, stream>>>(bufG, rowptr, col, dinv, bb2, N, 1, bufH);
    // layer 3 (no relu)
    gemm_mfma<<<gemm_grid, 256, 0, stream>>>(bufH, W3, dinv, N, bufG);
    gather16<<<gather_grid, 256, 0, stream>>>(bufG, rowptr, col, dinv, bb3, N, 0, bufH);

    // pooling + MLP head
    pool_part<<<(N + PCH - 1) / PCH, 128, 0, stream>>>(bufH, batch, N, pooled);
    mlp1g<<<G, 256, 0, stream>>>(pooled, gstart, Wm1, bm1, Obuf);
    mlp2g<<<G, 768, 0, stream>>>(Obuf, Wm2, bm2, (float*)d_out);
}